// Round 1
// 615.431 us; speedup vs baseline: 1.2117x; 1.2117x over previous
//
#include <hip/hip_runtime.h>
#include <hip/hip_bf16.h>
#include <math.h>

#define BATCH 8192
#define IN_DIM 1024
#define H_DIM 2048
#define NHEAD 4
#define HEAD_DIM 512
#define EPS_LN 1e-5f

// 256x256 tile, K-step 32, 4-deep LDS ring (128 KiB), 8 waves (2M x 4N).
#define BM 256
#define BN 256
#define BKQ 32
#define NBUF 4

typedef __bf16 bf16x8 __attribute__((ext_vector_type(8)));
typedef short s16x8 __attribute__((ext_vector_type(8)));
typedef float f32x4 __attribute__((ext_vector_type(4)));

__device__ __forceinline__ float b2f(short s) {
  union { unsigned u; float f; } v;
  v.u = ((unsigned)(unsigned short)s) << 16;
  return v.f;
}
__device__ __forceinline__ short f2b(float f) {
  union { float f; unsigned u; } v;
  v.f = f;
  unsigned r = v.u + 0x7fffu + ((v.u >> 16) & 1u);
  return (short)(r >> 16);
}

__device__ __forceinline__ void async_ld16(const short* g, const short* l) {
  __builtin_amdgcn_global_load_lds(
      (const __attribute__((address_space(1))) void*)g,
      (__attribute__((address_space(3))) void*)l, 16, 0, 0);
}

// fp32 -> bf16 (rne), 8 elements/thread
__global__ __launch_bounds__(256) void cvt_k(const float* __restrict__ s,
                                             short* __restrict__ d, int n) {
  int i = (blockIdx.x * 256 + threadIdx.x) * 8;
  if (i >= n) return;
  f32x4 a = *(const f32x4*)(s + i);
  f32x4 b = *(const f32x4*)(s + i + 4);
  s16x8 o;
#pragma unroll
  for (int j = 0; j < 4; j++) o[j] = f2b(a[j]);
#pragma unroll
  for (int j = 0; j < 4; j++) o[4 + j] = f2b(b[j]);
  *(s16x8*)(d + i) = o;
}

enum { EPI_BIAS = 0, EPI_GELU = 1, EPI_GATE = 2 };

// Stage one K-tile (A 256x32 + B 256x32 bf16) into LDS ring slot t&3.
// LDS dest is linear (global_load_lds requirement); bank-conflict swizzle
// byte^=(row&3)<<4 is applied by inverse-permuting the GLOBAL source column
// (rule: linear dest + inv-swz source + swz on read).
// Per wave: rows [wv*32, wv*32+32) of both A and B; 4 loads/thread/tile.
template <bool DUAL>
__device__ __forceinline__ void stage_tile(
    const short* __restrict__ A, const short* __restrict__ A2,
    const short* __restrict__ W, short* __restrict__ lds, int t, int K,
    int lda, int rowBase, int colBase, int wv, int rsub, int swz) {
  const int k0 = t * BKQ;
  const short* Asrc = A;
  int ak = k0;
  if (DUAL && k0 >= H_DIM) { Asrc = A2; ak = k0 - H_DIM; }
  short* As = lds + (t & (NBUF - 1)) * (BM * BKQ);
  short* Bs = lds + NBUF * BM * BKQ + (t & (NBUF - 1)) * (BN * BKQ);
  const int r0 = wv * 32;
#pragma unroll
  for (int c = 0; c < 2; c++) {
    const int ra = r0 + c * 16 + rsub;
    async_ld16(Asrc + (size_t)(rowBase + ra) * lda + ak + swz,
               As + (r0 + c * 16) * BKQ);
    async_ld16(W + (size_t)(colBase + ra) * K + k0 + swz,
               Bs + (r0 + c * 16) * BKQ);
  }
}

// C[M,N] = A[M,K] * W[N,K]^T + bias.  A,W bf16; bias fp32.
// EPI_BIAS/GELU: C is bf16 (short*). EPI_GATE: C is fp32 (float*), fuses
// sigmoid(gate) + layernorm + blend.  DUAL: k<H_DIM from A, k>=H_DIM from A2.
// Pipeline: 4-deep LDS ring, stage tile t+3 while computing tile t; counted
// vmcnt(8) (never drains in steady state) + raw s_barrier.  Race-freedom:
// buffer (t+3)&3 == (t-1)&3 was fully consumed (lgkmcnt(0)) by every wave
// before the barrier ending iter t-1; tile t is fully landed because every
// wave's vmcnt at end of iter t-1 covers its own share of tile t's loads.
template <int EPI, bool DUAL>
__global__ __launch_bounds__(512, 2) void gemm_bt(
    const short* __restrict__ A, const short* __restrict__ A2,
    const short* __restrict__ W, const float* __restrict__ bias,
    void* __restrict__ Cv, int K, int lda,
    const short* __restrict__ attg, const float* __restrict__ hprev,
    const float* __restrict__ mu, const float* __restrict__ rstd,
    const float* __restrict__ gamma, const float* __restrict__ beta) {
  extern __shared__ __attribute__((aligned(16))) short lds[];
  const int tid = threadIdx.x;
  const int wv = tid >> 6;
  const int lane = tid & 63;
  // XCD-aware remap: flat dispatch index mod 8 ~ XCD; give each XCD one
  // full N-panel row (gridDim.y == 8 == NXCD) so its 2MB W panel L2-resides.
  const int f = blockIdx.y * gridDim.x + blockIdx.x;
  const int ty = f & 7;
  const int tx = f >> 3;
  const int rowBase = tx * BM;
  const int colBase = ty * BN;
  const int wm = wv >> 2;  // 0..1
  const int wn = wv & 3;   // 0..3
  const int fr = lane & 15;
  const int rsub = lane >> 2;
  const int swz = ((lane & 3) ^ ((lane >> 2) & 3)) << 3;   // staging src perm (elems)
  const int cbt = ((lane >> 4) ^ (lane & 3)) << 3;         // read-side swz (elems)
  const int NT = K / BKQ;

  f32x4 acc[8][4] = {};

  stage_tile<DUAL>(A, A2, W, lds, 0, K, lda, rowBase, colBase, wv, rsub, swz);
  stage_tile<DUAL>(A, A2, W, lds, 1, K, lda, rowBase, colBase, wv, rsub, swz);
  stage_tile<DUAL>(A, A2, W, lds, 2, K, lda, rowBase, colBase, wv, rsub, swz);
  asm volatile("s_waitcnt vmcnt(8)" ::: "memory");  // tile 0 landed
  __builtin_amdgcn_s_barrier();
  asm volatile("" ::: "memory");

  for (int t = 0; t < NT; ++t) {
    if (t + 3 < NT)
      stage_tile<DUAL>(A, A2, W, lds, t + 3, K, lda, rowBase, colBase, wv,
                       rsub, swz);

    const short* As = lds + (t & (NBUF - 1)) * (BM * BKQ);
    const short* Bs = lds + NBUF * BM * BKQ + (t & (NBUF - 1)) * (BN * BKQ);
    bf16x8 af[8], bfr[4];
    const short* ap = As + (wm * 128 + fr) * BKQ + cbt;
#pragma unroll
    for (int mi = 0; mi < 8; mi++)
      af[mi] = *(const bf16x8*)(ap + mi * (16 * BKQ));
    const short* bp = Bs + (wn * 64 + fr) * BKQ + cbt;
#pragma unroll
    for (int ni = 0; ni < 4; ni++)
      bfr[ni] = *(const bf16x8*)(bp + ni * (16 * BKQ));

    __builtin_amdgcn_s_setprio(1);
#pragma unroll
    for (int mi = 0; mi < 8; mi++)
#pragma unroll
      for (int ni = 0; ni < 4; ni++)
        acc[mi][ni] = __builtin_amdgcn_mfma_f32_16x16x32_bf16(
            af[mi], bfr[ni], acc[mi][ni], 0, 0, 0);
    __builtin_amdgcn_s_setprio(0);

    if (t + 1 < NT) {
      // lgkmcnt(0): this wave's LDS reads fully returned before the barrier,
      // so post-barrier staging of buffer (t+4)&3 cannot race any reader.
      // vmcnt leaves tiles beyond t+1 in flight (8 = 2 tiles x 4 loads).
      if (t + 3 < NT)
        asm volatile("s_waitcnt vmcnt(8) lgkmcnt(0)" ::: "memory");
      else if (t + 2 < NT)
        asm volatile("s_waitcnt vmcnt(4) lgkmcnt(0)" ::: "memory");
      else
        asm volatile("s_waitcnt vmcnt(0) lgkmcnt(0)" ::: "memory");
      __builtin_amdgcn_s_barrier();
      asm volatile("" ::: "memory");
    }
  }

  // C/D layout: col = lane&15, row = (lane>>4)*4 + reg.
  const int ocol0 = colBase + wn * 64 + fr;
  const int orow0 = rowBase + wm * 128 + ((lane >> 4) << 2);
#pragma unroll
  for (int mi = 0; mi < 8; mi++) {
#pragma unroll
    for (int ni = 0; ni < 4; ni++) {
      const int col = ocol0 + ni * 16;
      const float bia = bias[col];
#pragma unroll
      for (int r = 0; r < 4; r++) {
        const int row = orow0 + mi * 16 + r;
        float v = acc[mi][ni][r] + bia;
        const size_t idx = (size_t)row * H_DIM + col;
        if (EPI == EPI_BIAS) {
          ((short*)Cv)[idx] = f2b(v);
        } else if (EPI == EPI_GELU) {
          float g = 0.5f * v * (1.0f + erff(v * 0.70710678118654752f));
          ((short*)Cv)[idx] = f2b(g);
        } else {
          float gate = 1.0f / (1.0f + expf(-v));
          float hp = hprev[idx];
          float y = hp + b2f(attg[idx]);
          float hc = (y - mu[row]) * rstd[row] * gamma[col] + beta[col];
          ((float*)Cv)[idx] = gate * hc + (1.0f - gate) * hp;
        }
      }
    }
  }
}

// One wave per (b, head). Keys: k1=h, k2=xp, k3=h+xp, k4=h*xp; s3=s1+s2.
// q (bf16) read from `qa`, attn written back over `qa` in place (safe: each
// lane reads its slot before writing it). h read in fp32.
__global__ __launch_bounds__(256) void attn_k(short* __restrict__ qa,
                                              const float* __restrict__ h,
                                              const short* __restrict__ xp) {
  const int lane = threadIdx.x & 63;
  const int pair = blockIdx.x * 4 + (threadIdx.x >> 6);  // b*NH + head
  const size_t base =
      (size_t)(pair >> 2) * H_DIM + (size_t)(pair & 3) * HEAD_DIM + lane * 8;
  s16x8 qv = *(const s16x8*)(qa + base);
  f32x4 h0 = *(const f32x4*)(h + base);
  f32x4 h1 = *(const f32x4*)(h + base + 4);
  s16x8 xv = *(const s16x8*)(xp + base);
  float hf[8], xf[8];
  float s1 = 0.f, s2 = 0.f, s4 = 0.f;
#pragma unroll
  for (int j = 0; j < 8; j++) {
    float qf = b2f(qv[j]);
    hf[j] = (j < 4) ? h0[j] : h1[j - 4];
    xf[j] = b2f(xv[j]);
    s1 += qf * hf[j];
    s2 += qf * xf[j];
    s4 += qf * hf[j] * xf[j];
  }
#pragma unroll
  for (int off = 32; off > 0; off >>= 1) {
    s1 += __shfl_xor(s1, off, 64);
    s2 += __shfl_xor(s2, off, 64);
    s4 += __shfl_xor(s4, off, 64);
  }
  const float scale = 0.04419417382415922f;  // 1/sqrt(512)
  float t1 = s1 * scale, t2 = s2 * scale, t3 = (s1 + s2) * scale, t4 = s4 * scale;
  float mx = fmaxf(fmaxf(t1, t2), fmaxf(t3, t4));
  float e1 = expf(t1 - mx), e2 = expf(t2 - mx), e3 = expf(t3 - mx), e4 = expf(t4 - mx);
  float inv = 1.0f / (e1 + e2 + e3 + e4);
  float w1 = e1 * inv, w2 = e2 * inv, w3 = e3 * inv, w4 = e4 * inv;
  float ch = w1 + w3, cx = w2 + w3;
  s16x8 o;
#pragma unroll
  for (int j = 0; j < 8; j++)
    o[j] = f2b(ch * hf[j] + cx * xf[j] + w4 * hf[j] * xf[j]);
  *(s16x8*)(qa + base) = o;
}

// Per-row mean / rstd of (attg(bf16) + h(fp32)).
__global__ __launch_bounds__(256) void rowstats_k(
    const short* __restrict__ attg, const float* __restrict__ h,
    float* __restrict__ mu, float* __restrict__ rstd) {
  __shared__ float sm[8];
  const int row = blockIdx.x;
  const int tid = threadIdx.x;
  const size_t base = (size_t)row * H_DIM + tid * 8;
  s16x8 a = *(const s16x8*)(attg + base);
  f32x4 h0 = *(const f32x4*)(h + base);
  f32x4 h1 = *(const f32x4*)(h + base + 4);
  float s = 0.f, ss = 0.f;
#pragma unroll
  for (int j = 0; j < 8; j++) {
    float y = b2f(a[j]) + ((j < 4) ? h0[j] : h1[j - 4]);
    s += y;
    ss += y * y;
  }
#pragma unroll
  for (int off = 32; off > 0; off >>= 1) {
    s += __shfl_xor(s, off, 64);
    ss += __shfl_xor(ss, off, 64);
  }
  if ((tid & 63) == 0) {
    sm[tid >> 6] = s;
    sm[4 + (tid >> 6)] = ss;
  }
  __syncthreads();
  if (tid == 0) {
    float S = sm[0] + sm[1] + sm[2] + sm[3];
    float SS = sm[4] + sm[5] + sm[6] + sm[7];
    float m = S * (1.0f / H_DIM);
    float var = SS * (1.0f / H_DIM) - m * m;
    mu[row] = m;
    rstd[row] = rsqrtf(fmaxf(var, 0.0f) + EPS_LN);
  }
}

extern "C" void kernel_launch(void* const* d_in, const int* in_sizes, int n_in,
                              void* d_out, int out_size, void* d_ws,
                              size_t ws_size, hipStream_t stream) {
  (void)in_sizes; (void)n_in; (void)out_size; (void)ws_size;
  const float* h_prev = (const float*)d_in[0];
  const float* x      = (const float*)d_in[1];
  const float* W_proj = (const float*)d_in[2];
  const float* b_proj = (const float*)d_in[3];
  const float* W_q    = (const float*)d_in[4];
  const float* b_q    = (const float*)d_in[5];
  const float* W_o    = (const float*)d_in[6];
  const float* b_o    = (const float*)d_in[7];
  const float* W_g    = (const float*)d_in[8];
  const float* b_g    = (const float*)d_in[9];
  const float* gamma  = (const float*)d_in[10];
  const float* beta   = (const float*)d_in[11];
  float* out = (float*)d_out;

  const size_t BH = (size_t)BATCH * H_DIM;       // 16,777,216
  const size_t BI = (size_t)BATCH * IN_DIM;      // 8,388,608
  const size_t NWP = (size_t)H_DIM * IN_DIM;     // 2,097,152
  const size_t NWQ = (size_t)H_DIM * H_DIM;      // 4,194,304
  const size_t NWG = (size_t)H_DIM * 2 * H_DIM;  // 8,388,608

  short* h_bf = (short*)d_ws;
  short* x_bf = h_bf + BH;
  short* wp   = x_bf + BI;
  short* wq   = wp + NWP;
  short* wo   = wq + NWQ;
  short* wg   = wo + NWQ;
  short* bufA = wg + NWG;   // xp, later attn_g
  short* bufB = bufA + BH;  // q, later attn (in place)
  float* mu   = (float*)(bufB + BH);
  float* rstd = mu + BATCH;

  dim3 blk(512);
  dim3 grd(BATCH / BM, H_DIM / BN);  // (32, 8)
  const int SMEM = 2 * NBUF * BM * BKQ * (int)sizeof(short);  // 131072
  (void)hipFuncSetAttribute((const void*)gemm_bt<EPI_BIAS, false>,
                            hipFuncAttributeMaxDynamicSharedMemorySize, SMEM);
  (void)hipFuncSetAttribute((const void*)gemm_bt<EPI_GELU, false>,
                            hipFuncAttributeMaxDynamicSharedMemorySize, SMEM);
  (void)hipFuncSetAttribute((const void*)gemm_bt<EPI_GATE, true>,
                            hipFuncAttributeMaxDynamicSharedMemorySize, SMEM);

  dim3 cblk(256);
#define CVT(src, dst, n) \
  cvt_k<<<dim3(((n) / 8 + 255) / 256), cblk, 0, stream>>>(src, dst, (int)(n))

  CVT(h_prev, h_bf, BH);
  CVT(x, x_bf, BI);
  CVT(W_proj, wp, NWP);
  CVT(W_q, wq, NWQ);
  CVT(W_o, wo, NWQ);
  CVT(W_g, wg, NWG);
#undef CVT

  // 1. xp = x @ W_proj^T + b_proj
  gemm_bt<EPI_BIAS, false><<<grd, blk, SMEM, stream>>>(
      x_bf, nullptr, wp, b_proj, bufA, IN_DIM, IN_DIM,
      nullptr, nullptr, nullptr, nullptr, nullptr, nullptr);
  // 2. q = h @ W_q^T + b_q
  gemm_bt<EPI_BIAS, false><<<grd, blk, SMEM, stream>>>(
      h_bf, nullptr, wq, b_q, bufB, H_DIM, H_DIM,
      nullptr, nullptr, nullptr, nullptr, nullptr, nullptr);
  // 3. attention -> bufB (in place over q)
  attn_k<<<dim3(BATCH * NHEAD / 4), cblk, 0, stream>>>(bufB, h_prev, bufA);
  // 4. attn_g = gelu(attn @ W_o^T + b_o) -> bufA
  gemm_bt<EPI_GELU, false><<<grd, blk, SMEM, stream>>>(
      bufB, nullptr, wo, b_o, bufA, H_DIM, H_DIM,
      nullptr, nullptr, nullptr, nullptr, nullptr, nullptr);
  // 5. layernorm stats of (attn_g + h_prev)
  rowstats_k<<<dim3(BATCH), cblk, 0, stream>>>(bufA, h_prev, mu, rstd);
  // 6. gate GEMM (K=4096 over [h, attn_g]) + fused sigmoid/LN/blend -> out
  gemm_bt<EPI_GATE, true><<<grd, blk, SMEM, stream>>>(
      h_bf, bufA, wg, b_g, out, 2 * H_DIM, H_DIM,
      bufA, h_prev, mu, rstd, gamma, beta);
}